// Round 10
// baseline (164.056 us; speedup 1.0000x reference)
//
#include <hip/hip_runtime.h>
#include <hip/hip_bf16.h>
#include <stdint.h>

#define B_DIM 8192
#define I_DIM 1024
#define H_DIM 1024

typedef __attribute__((ext_vector_type(8))) short short8;
typedef __attribute__((ext_vector_type(4))) float f32x4;

static __device__ __forceinline__ short f2b(float f) {
    __bf16 h = (__bf16)f;
    return __builtin_bit_cast(short, h);
}

static __device__ __forceinline__ short8 pack8(float4 a, float4 b) {
    short8 s;
    s[0] = f2b(a.x); s[1] = f2b(a.y); s[2] = f2b(a.z); s[3] = f2b(a.w);
    s[4] = f2b(b.x); s[5] = f2b(b.y); s[6] = f2b(b.z); s[7] = f2b(b.w);
    return s;
}

static __device__ __forceinline__ float sigmoid_f(float x) {
    return 1.0f / (1.0f + __expf(-x));
}

static __device__ __forceinline__ float tanh_fast(float x) {
    x = fminf(fmaxf(x, -15.0f), 15.0f);
    float e = __expf(2.0f * x);
    return (e - 1.0f) / (e + 1.0f);
}

static __device__ __forceinline__ void load_lds16(const void* gptr, void* lptr) {
    __builtin_amdgcn_global_load_lds(
        (const __attribute__((address_space(1))) uint32_t*)gptr,
        (__attribute__((address_space(3))) uint32_t*)lptr, 16, 0, 0);
}

// ---------------------------------------------------------------------------
// Pass 1: fp32 -> bf16 conversion into FRAGMENT-ORDERED workspace (unchanged).
//   A_fw: [mfrag 0..511][k32 0..63][lane 0..63][8 bf16]
//         row = mfrag*16 + (lane&15), k = k32*32 + (lane>>4)*8
//   B_fw: [nfrag 0..255][k32][lane][8]
//         nfrag = bn*16 + cf; gate = cf&3; col = bn*64 + (cf>>2)*16 + (lane&15)
// ---------------------------------------------------------------------------
#define GA_GROUPS (512 * 32 * 2 * 64)   // 2,097,152  (A 16B-groups)
#define GB_GROUPS (256 * 32 * 2 * 64)   // 1,048,576  (B 16B-groups)

__global__ __launch_bounds__(256) void convert_kernel(
    const float* __restrict__ x, const float* __restrict__ h,
    const float* __restrict__ wx, const float* __restrict__ wh,
    short* __restrict__ Aw, short* __restrict__ Bw)
{
    const int64_t total = (int64_t)GA_GROUPS + GB_GROUPS;
    for (int64_t g = (int64_t)blockIdx.x * blockDim.x + threadIdx.x; g < total;
         g += (int64_t)gridDim.x * blockDim.x) {
        const float* src;
        short* dst;
        if (g < GA_GROUPS) {
            const int lane = (int)(g & 63);
            const int rest = (int)(g >> 6);
            const int kh   = rest & 1;
            const int tk   = (rest >> 1) & 31;
            const int mfrag = rest >> 6;
            const int row = (mfrag << 4) + (lane & 15);
            const int k   = (tk << 6) + (kh << 5) + ((lane >> 4) << 3);
            src = (k < 1024) ? (x + (size_t)row * 1024 + k)
                             : (h + (size_t)row * 1024 + (k - 1024));
            dst = Aw + (size_t)g * 8;
        } else {
            const int64_t gb = g - GA_GROUPS;
            const int lane = (int)(gb & 63);
            const int rest = (int)(gb >> 6);
            const int kh   = rest & 1;
            const int tk   = (rest >> 1) & 31;
            const int nfrag = rest >> 6;
            const int cf   = nfrag & 15;
            const int bn   = nfrag >> 4;
            const int gate = cf & 3;
            const int col  = (bn << 6) + ((cf >> 2) << 4) + (lane & 15);
            const int k    = (tk << 6) + (kh << 5) + ((lane >> 4) << 3);
            src = (k < 1024) ? (wx + ((size_t)(gate << 10) + col) * 1024 + k)
                             : (wh + ((size_t)(gate << 10) + col) * 1024 + (k - 1024));
            dst = Bw + (size_t)gb * 8;
        }
        float4 v0 = ((const float4*)src)[0];
        float4 v1 = ((const float4*)src)[1];
        *(short8*)dst = pack8(v0, v1);
    }
}

// ---------------------------------------------------------------------------
// Pass 2: 128x128-tile GEMM, BK=32, 4 waves/block, 4 blocks/CU.
// B goes GLOBAL->REGISTER directly (fragment-ordered workspace IS the register
// layout; re-reads served by per-XCD L2 where the 2 MB B-slice is resident).
// Only A is staged through LDS -> LDS traffic halves (was the bottleneck:
// ~6.3 GB at ~52 TB/s ≈ 120 us of the 137 us kernel).
// LDS: [2 dbuf][8 A-frags][512 shorts] = 16 KiB.
// One vmcnt(0)+barrier per k32-tile (order-robust, race-proof).
// Fused in-register LSTM epilogue.
// ---------------------------------------------------------------------------
#define AOFF(d, f) ((d) * 4096 + (f) * 512)

__global__ __launch_bounds__(256, 4) void lstm_gemm_bd_kernel(
    const short* __restrict__ Aw, const short* __restrict__ Bw,
    const float* __restrict__ cprev, const float* __restrict__ bh,
    float* __restrict__ out)
{
    __shared__ __align__(16) short smem[8192];   // 16 KiB

    // XCD-aware: hw round-robins blockIdx -> XCD (xcd = bid&7). Each XCD works
    // h-tiles 4*xcd..4*xcd+3 (2 MB B-slice L2-resident); consecutive c share
    // the same A-panel (c>>2 = bm) for L2 temporal locality on A.
    const int bid = blockIdx.x;
    const int xcd = bid & 7;
    const int c   = bid >> 3;            // 0..255 within XCD
    const int bm  = c >> 2;              // 0..63  (128-row M tile)
    const int ht  = 4 * xcd + (c & 3);   // 0..31  (32-h N tile)
    const int m0  = bm * 128;

    const int t    = threadIdx.x;
    const int lane = t & 63;
    const int w    = t >> 6;     // wave 0..3
    const int wm   = w >> 1;     // 0..1  M half
    const int wn   = w & 1;      // 0..1  N half (16-h group)
    const int lc   = lane & 15;

    // A staging sources (contiguous 1 KiB per gload_lds): wave w stages
    // A-frags 2w, 2w+1. Frag stride = 64 k32-tiles * 512 shorts = 32768.
    const short* aSrc0 = Aw + (size_t)(bm * 8 + 2 * w)     * 32768 + lane * 8;
    const short* aSrc1 = Aw + (size_t)(bm * 8 + 2 * w + 1) * 32768 + lane * 8;
    // B register-load base: frags ht*8 + wn*4 + j (j = gate 0..3)
    const short* bBase = Bw + (size_t)(ht * 8 + wn * 4) * 32768 + lane * 8;

    f32x4 acc[4][4] = {};   // [m-frag][gate]
    short8 bvA[4], bvB[4];  // B register double-buffer (static names)

    // prologue: stage A k32-tile 0 into dbuf 0; load B(0) into bvA
    load_lds16(aSrc0, &smem[AOFF(0, 2 * w)]);
    load_lds16(aSrc1, &smem[AOFF(0, 2 * w + 1)]);
    #pragma unroll
    for (int j = 0; j < 4; ++j)
        bvA[j] = *(const short8*)(bBase + (size_t)j * 32768);
    asm volatile("s_waitcnt vmcnt(0)" ::: "memory");
    __builtin_amdgcn_s_barrier();

#define TILE(d, tp, BC, BN) do { \
    short8 av[4]; \
    _Pragma("unroll") \
    for (int i = 0; i < 4; ++i) \
        av[i] = *(const short8*)&smem[AOFF(d, wm * 4 + i) + lane * 8]; \
    load_lds16(aSrc0 + (tp) * 512, &smem[AOFF(d ^ 1, 2 * w)]); \
    load_lds16(aSrc1 + (tp) * 512, &smem[AOFF(d ^ 1, 2 * w + 1)]); \
    _Pragma("unroll") \
    for (int j = 0; j < 4; ++j) \
        BN[j] = *(const short8*)(bBase + (size_t)j * 32768 + (size_t)(tp) * 512); \
    __builtin_amdgcn_s_setprio(1); \
    _Pragma("unroll") \
    for (int i = 0; i < 4; ++i) \
        _Pragma("unroll") \
        for (int j = 0; j < 4; ++j) \
            acc[i][j] = __builtin_amdgcn_mfma_f32_16x16x32_bf16( \
                av[i], BC[j], acc[i][j], 0, 0, 0); \
    __builtin_amdgcn_s_setprio(0); \
    asm volatile("s_waitcnt vmcnt(0)" ::: "memory"); \
    __builtin_amdgcn_s_barrier(); \
} while (0)

    #pragma unroll 1
    for (int tk2 = 0; tk2 < 32; ++tk2) {
        const int t1 = 2 * tk2 + 1;
        const int t2 = (t1 + 1 < 64) ? t1 + 1 : 63;
        TILE(0, t1, bvA, bvB);
        TILE(1, t2, bvB, bvA);
    }
#undef TILE

    // ---- fused LSTM epilogue, in-register ----
    // D layout: col = lane&15 (h), row = (lane>>4)*4 + reg
    const int rg = lane >> 4;
    const int h  = ht * 32 + wn * 16 + lc;
    const float b_i = bh[0 * H_DIM + h];
    const float b_f = bh[1 * H_DIM + h];
    const float b_g = bh[2 * H_DIM + h];
    const float b_o = bh[3 * H_DIM + h];

    #pragma unroll
    for (int mf = 0; mf < 4; ++mf) {
        #pragma unroll
        for (int r = 0; r < 4; ++r) {
            const int row = m0 + wm * 64 + mf * 16 + rg * 4 + r;
            const float pi = acc[mf][0][r] + b_i;
            const float pf = acc[mf][1][r] + b_f;
            const float pg = acc[mf][2][r] + b_g;
            const float po = acc[mf][3][r] + b_o;
            const float iv = sigmoid_f(pi);
            const float fv = sigmoid_f(pf);
            const float gv = tanh_fast(pg);
            const float ov = sigmoid_f(po);
            const float cp = cprev[(size_t)row * H_DIM + h];
            const float cn = fv * cp + iv * gv;
            const float hn = ov * tanh_fast(cn);
            out[(size_t)row * H_DIM + h] = hn;
            out[(size_t)B_DIM * H_DIM + (size_t)row * H_DIM + h] = cn;
        }
    }
}

// ---------------------------------------------------------------------------
// Fallback (no workspace) — kept for safety.
// ---------------------------------------------------------------------------
static __device__ __forceinline__ int swz(int row, int k) {
    int byte = (row << 7) + (k << 1);
    byte ^= (row & 7) << 4;
    return byte >> 1;
}

__global__ __launch_bounds__(256, 2) void lstm_fallback_kernel(
    const float* __restrict__ x, const float* __restrict__ hprev,
    const float* __restrict__ cprev, const float* __restrict__ Wx,
    const float* __restrict__ Wh, const float* __restrict__ bh,
    float* __restrict__ out)
{
    __shared__ __align__(16) short As[128 * 64];
    __shared__ __align__(16) short Bs[128 * 64];

    int bid = blockIdx.x;
    bid = (bid & 7) * 256 + (bid >> 3);
    const int mt = bid >> 5;
    const int ht = bid & 31;
    const int m0 = mt * 128;
    const int h0 = ht * 32;

    const int t    = threadIdx.x;
    const int lane = t & 63;
    const int w    = t >> 6;
    const int wr   = w >> 1;
    const int wc   = w & 1;

    const int srow = t >> 3;
    const int sk   = (t & 7) * 8;

    f32x4 acc[4][4] = {};

    #pragma unroll 1
    for (int phase = 0; phase < 2; ++phase) {
        const float* __restrict__ Ap = phase ? hprev : x;
        const float* __restrict__ Bp = phase ? Wh : Wx;
        #pragma unroll 1
        for (int kk = 0; kk < 1024; kk += 64) {
            __syncthreads();
            #pragma unroll
            for (int p = 0; p < 4; ++p) {
                const int row = srow + p * 32;
                const float4* src = (const float4*)(Ap + (size_t)(m0 + row) * I_DIM + kk + sk);
                *(short8*)&As[swz(row, sk)] = pack8(src[0], src[1]);
            }
            #pragma unroll
            for (int p = 0; p < 4; ++p) {
                const int n    = srow + p * 32;
                const int gate = (n >> 4) & 3;
                const int hcol = h0 + ((n >> 6) << 4) + (n & 15);
                const float4* src = (const float4*)(Bp + (size_t)((gate << 10) + hcol) * 1024 + kk + sk);
                *(short8*)&Bs[swz(n, sk)] = pack8(src[0], src[1]);
            }
            __syncthreads();
            #pragma unroll
            for (int ks = 0; ks < 2; ++ks) {
                const int kb = ks * 32 + ((lane >> 4) << 3);
                short8 a[4], b[4];
                #pragma unroll
                for (int m = 0; m < 4; ++m)
                    a[m] = *(const short8*)&As[swz(wr * 64 + m * 16 + (lane & 15), kb)];
                #pragma unroll
                for (int j = 0; j < 4; ++j)
                    b[j] = *(const short8*)&Bs[swz(wc * 64 + j * 16 + (lane & 15), kb)];
                #pragma unroll
                for (int m = 0; m < 4; ++m)
                    #pragma unroll
                    for (int j = 0; j < 4; ++j)
                        acc[m][j] = __builtin_amdgcn_mfma_f32_16x16x32_bf16(a[m], b[j], acc[m][j], 0, 0, 0);
            }
        }
    }

    const int cl = lane & 15;
    const int rg = lane >> 4;
    const int h  = h0 + wc * 16 + cl;
    const float b_i = bh[0 * H_DIM + h];
    const float b_f = bh[1 * H_DIM + h];
    const float b_g = bh[2 * H_DIM + h];
    const float b_o = bh[3 * H_DIM + h];

    #pragma unroll
    for (int m = 0; m < 4; ++m) {
        #pragma unroll
        for (int r = 0; r < 4; ++r) {
            const int row = m0 + wr * 64 + m * 16 + rg * 4 + r;
            const float pi = acc[m][0][r] + b_i;
            const float pf = acc[m][1][r] + b_f;
            const float pg = acc[m][2][r] + b_g;
            const float po = acc[m][3][r] + b_o;
            const float iv = sigmoid_f(pi);
            const float fv = sigmoid_f(pf);
            const float gv = tanh_fast(pg);
            const float ov = sigmoid_f(po);
            const float cp = cprev[(size_t)row * H_DIM + h];
            const float cn = fv * cp + iv * gv;
            const float hn = ov * tanh_fast(cn);
            out[(size_t)row * H_DIM + h] = hn;
            out[(size_t)B_DIM * H_DIM + (size_t)row * H_DIM + h] = cn;
        }
    }
}

extern "C" void kernel_launch(void* const* d_in, const int* in_sizes, int n_in,
                              void* d_out, int out_size, void* d_ws, size_t ws_size,
                              hipStream_t stream) {
    const float* x     = (const float*)d_in[0];
    const float* hprev = (const float*)d_in[1];
    const float* cprev = (const float*)d_in[2];
    const float* Wx    = (const float*)d_in[3];
    const float* Wh    = (const float*)d_in[4];
    const float* bh    = (const float*)d_in[5];
    float* out = (float*)d_out;

    const size_t need = ((size_t)B_DIM * 2048 + (size_t)4096 * 2048) * sizeof(short);
    if (ws_size >= need && d_ws != nullptr) {
        short* Aw = (short*)d_ws;                 // A_fw: 512 frags * 32768 shorts
        short* Bw = Aw + (size_t)512 * 32768;     // B_fw: 256 frags * 32768 shorts
        hipLaunchKernelGGL(convert_kernel, dim3(4096), dim3(256), 0, stream,
                           x, hprev, Wx, Wh, Aw, Bw);
        hipLaunchKernelGGL(lstm_gemm_bd_kernel, dim3(2048), dim3(256), 0, stream,
                           Aw, Bw, cprev, bh, out);
    } else {
        hipLaunchKernelGGL(lstm_fallback_kernel, dim3(2048), dim3(256), 0, stream,
                           x, hprev, cprev, Wx, Wh, bh, out);
    }
}

// Round 11
// 151.422 us; speedup vs baseline: 1.0834x; 1.0834x over previous
//
#include <hip/hip_runtime.h>
#include <hip/hip_bf16.h>
#include <stdint.h>

#define B_DIM 8192
#define I_DIM 1024
#define H_DIM 1024

typedef __attribute__((ext_vector_type(8))) short short8;
typedef __attribute__((ext_vector_type(4))) float f32x4;

static __device__ __forceinline__ short f2b(float f) {
    __bf16 h = (__bf16)f;
    return __builtin_bit_cast(short, h);
}

static __device__ __forceinline__ short8 pack8(float4 a, float4 b) {
    short8 s;
    s[0] = f2b(a.x); s[1] = f2b(a.y); s[2] = f2b(a.z); s[3] = f2b(a.w);
    s[4] = f2b(b.x); s[5] = f2b(b.y); s[6] = f2b(b.z); s[7] = f2b(b.w);
    return s;
}

static __device__ __forceinline__ float sigmoid_f(float x) {
    return 1.0f / (1.0f + __expf(-x));
}

static __device__ __forceinline__ float tanh_fast(float x) {
    x = fminf(fmaxf(x, -15.0f), 15.0f);
    float e = __expf(2.0f * x);
    return (e - 1.0f) / (e + 1.0f);
}

static __device__ __forceinline__ void load_lds16(const void* gptr, void* lptr) {
    __builtin_amdgcn_global_load_lds(
        (const __attribute__((address_space(1))) uint32_t*)gptr,
        (__attribute__((address_space(3))) uint32_t*)lptr, 16, 0, 0);
}

// ---------------------------------------------------------------------------
// Pass 1: fp32 -> bf16 conversion into FRAGMENT-ORDERED workspace (unchanged).
//   A_fw: [mfrag 0..511][k32 0..63][lane 0..63][8 bf16]
//         row = mfrag*16 + (lane&15), k = k32*32 + (lane>>4)*8
//   B_fw: [nfrag 0..255][k32][lane][8]
//         nfrag = bn*16 + cf; gate = cf&3; col = bn*64 + (cf>>2)*16 + (lane&15)
// ---------------------------------------------------------------------------
#define GA_GROUPS (512 * 32 * 2 * 64)   // 2,097,152  (A 16B-groups)
#define GB_GROUPS (256 * 32 * 2 * 64)   // 1,048,576  (B 16B-groups)

__global__ __launch_bounds__(256) void convert_kernel(
    const float* __restrict__ x, const float* __restrict__ h,
    const float* __restrict__ wx, const float* __restrict__ wh,
    short* __restrict__ Aw, short* __restrict__ Bw)
{
    const int64_t total = (int64_t)GA_GROUPS + GB_GROUPS;
    for (int64_t g = (int64_t)blockIdx.x * blockDim.x + threadIdx.x; g < total;
         g += (int64_t)gridDim.x * blockDim.x) {
        const float* src;
        short* dst;
        if (g < GA_GROUPS) {
            const int lane = (int)(g & 63);
            const int rest = (int)(g >> 6);
            const int kh   = rest & 1;
            const int tk   = (rest >> 1) & 31;
            const int mfrag = rest >> 6;
            const int row = (mfrag << 4) + (lane & 15);
            const int k   = (tk << 6) + (kh << 5) + ((lane >> 4) << 3);
            src = (k < 1024) ? (x + (size_t)row * 1024 + k)
                             : (h + (size_t)row * 1024 + (k - 1024));
            dst = Aw + (size_t)g * 8;
        } else {
            const int64_t gb = g - GA_GROUPS;
            const int lane = (int)(gb & 63);
            const int rest = (int)(gb >> 6);
            const int kh   = rest & 1;
            const int tk   = (rest >> 1) & 31;
            const int nfrag = rest >> 6;
            const int cf   = nfrag & 15;
            const int bn   = nfrag >> 4;
            const int gate = cf & 3;
            const int col  = (bn << 6) + ((cf >> 2) << 4) + (lane & 15);
            const int k    = (tk << 6) + (kh << 5) + ((lane >> 4) << 3);
            src = (k < 1024) ? (wx + ((size_t)(gate << 10) + col) * 1024 + k)
                             : (wh + ((size_t)(gate << 10) + col) * 1024 + (k - 1024));
            dst = Bw + (size_t)gb * 8;
        }
        float4 v0 = ((const float4*)src)[0];
        float4 v1 = ((const float4*)src)[1];
        *(short8*)dst = pack8(v0, v1);
    }
}

// ---------------------------------------------------------------------------
// Pass 2: 128x128-tile GEMM, BK=32, 4 waves/block. COUNTED-vmcnt pipeline
// (T4): 3 rotating LDS buffers, stage issued 2 tiles ahead, per-tile
// "vmcnt(4) -> barrier -> stage(t+2) -> ds_read buf[t%3] -> 16 MFMA".
// Staging loads stay in flight ACROSS barriers; vmcnt never drains to 0 in
// the main loop, so HBM/L2 latency hides under ~2 tiles of MFMA work.
// 48 KiB LDS -> 3 blocks/CU. Fragment-ordered workspace (contiguous 1 KiB
// gload_lds), fragment-tile LDS (0 bank conflicts). Fused LSTM epilogue.
// LDS: [3 buf][ A 8 frags | B 8 frags ][512 shorts] = 48 KiB.
// ---------------------------------------------------------------------------
#define AOFF(d, f) ((d) * 8192 + (f) * 512)
#define BOFF(d, f) ((d) * 8192 + 4096 + (f) * 512)

__global__ __launch_bounds__(256, 3) void lstm_gemm_cnt_kernel(
    const short* __restrict__ Aw, const short* __restrict__ Bw,
    const float* __restrict__ cprev, const float* __restrict__ bh,
    float* __restrict__ out)
{
    __shared__ __align__(16) short smem[24576];   // 48 KiB

    // XCD-aware: hw round-robins blockIdx -> XCD (xcd = bid&7). Each XCD works
    // h-tiles 4*xcd..4*xcd+3 (2 MB B-slice L2-resident); the 4 consecutive
    // same-XCD blocks share one A-panel (c>>2 = bm) for A L2 temporal locality.
    const int bid = blockIdx.x;
    const int xcd = bid & 7;
    const int c   = bid >> 3;            // 0..255 within XCD
    const int bm  = c >> 2;              // 0..63  (128-row M tile)
    const int ht  = 4 * xcd + (c & 3);   // 0..31  (32-h N tile)
    const int m0  = bm * 128;

    const int t    = threadIdx.x;
    const int lane = t & 63;
    const int w    = t >> 6;     // wave 0..3
    const int wm   = w >> 1;     // 0..1  M half
    const int wn   = w & 1;      // 0..1  N half (16-h group)
    const int lc   = lane & 15;

    // staging sources (contiguous 1 KiB per gload_lds): wave w stages A-frags
    // 2w,2w+1 and B-frags 2w,2w+1. Frag stride = 64 k32-tiles * 512 shorts.
    const short* aSrc0 = Aw + (size_t)(bm * 8 + 2 * w)     * 32768 + lane * 8;
    const short* aSrc1 = Aw + (size_t)(bm * 8 + 2 * w + 1) * 32768 + lane * 8;
    const short* bSrc0 = Bw + (size_t)(ht * 8 + 2 * w)     * 32768 + lane * 8;
    const short* bSrc1 = Bw + (size_t)(ht * 8 + 2 * w + 1) * 32768 + lane * 8;

    f32x4 acc[4][4] = {};   // [m-frag][gate]

#define STAGE(db, tp) \
    load_lds16(aSrc0 + (tp) * 512, &smem[AOFF(db, 2 * w)]); \
    load_lds16(aSrc1 + (tp) * 512, &smem[AOFF(db, 2 * w + 1)]); \
    load_lds16(bSrc0 + (tp) * 512, &smem[BOFF(db, 2 * w)]); \
    load_lds16(bSrc1 + (tp) * 512, &smem[BOFF(db, 2 * w + 1)]);

// One k32-tile: wait only for the stage issued two tiles ago (4 newest loads
// = next tile's stage, left in flight), barrier, issue stage 2 ahead, read
// current buffer, MFMA. Exactly 4 VMEM loads per wave per tile.
#define TILE(db, sdb, tp) do { \
    asm volatile("s_waitcnt vmcnt(4)" ::: "memory"); \
    __builtin_amdgcn_s_barrier(); \
    STAGE(sdb, tp) \
    short8 bv[4], av[4]; \
    _Pragma("unroll") \
    for (int j = 0; j < 4; ++j) \
        bv[j] = *(const short8*)&smem[BOFF(db, wn * 4 + j) + lane * 8]; \
    _Pragma("unroll") \
    for (int i = 0; i < 4; ++i) \
        av[i] = *(const short8*)&smem[AOFF(db, wm * 4 + i) + lane * 8]; \
    __builtin_amdgcn_s_setprio(1); \
    _Pragma("unroll") \
    for (int i = 0; i < 4; ++i) \
        _Pragma("unroll") \
        for (int j = 0; j < 4; ++j) \
            acc[i][j] = __builtin_amdgcn_mfma_f32_16x16x32_bf16( \
                av[i], bv[j], acc[i][j], 0, 0, 0); \
    __builtin_amdgcn_s_setprio(0); \
} while (0)

    // prologue: stage tiles 0,1 into bufs 0,1 (8 loads outstanding)
    STAGE(0, 0)
    STAGE(1, 1)

    // tiles 0..62 in triples (buffer index compile-time), tile 63 separate
    #pragma unroll 1
    for (int tk3 = 0; tk3 < 21; ++tk3) {
        const int t0 = 3 * tk3;
        const int p2 = (t0 + 2 < 64) ? t0 + 2 : 63;
        const int p3 = (t0 + 3 < 64) ? t0 + 3 : 63;
        const int p4 = (t0 + 4 < 64) ? t0 + 4 : 63;
        TILE(0, 2, p2);
        TILE(1, 0, p3);
        TILE(2, 1, p4);
    }
    TILE(0, 2, 63);   // tile 63 reads buf 0 (staged at t=61); dummy stage
#undef TILE
#undef STAGE
    asm volatile("s_waitcnt vmcnt(0)" ::: "memory");

    // ---- fused LSTM epilogue, in-register ----
    // D layout: col = lane&15 (h), row = (lane>>4)*4 + reg
    const int rg = lane >> 4;
    const int h  = ht * 32 + wn * 16 + lc;
    const float b_i = bh[0 * H_DIM + h];
    const float b_f = bh[1 * H_DIM + h];
    const float b_g = bh[2 * H_DIM + h];
    const float b_o = bh[3 * H_DIM + h];

    #pragma unroll
    for (int mf = 0; mf < 4; ++mf) {
        #pragma unroll
        for (int r = 0; r < 4; ++r) {
            const int row = m0 + wm * 64 + mf * 16 + rg * 4 + r;
            const float pi = acc[mf][0][r] + b_i;
            const float pf = acc[mf][1][r] + b_f;
            const float pg = acc[mf][2][r] + b_g;
            const float po = acc[mf][3][r] + b_o;
            const float iv = sigmoid_f(pi);
            const float fv = sigmoid_f(pf);
            const float gv = tanh_fast(pg);
            const float ov = sigmoid_f(po);
            const float cp = cprev[(size_t)row * H_DIM + h];
            const float cn = fv * cp + iv * gv;
            const float hn = ov * tanh_fast(cn);
            out[(size_t)row * H_DIM + h] = hn;
            out[(size_t)B_DIM * H_DIM + (size_t)row * H_DIM + h] = cn;
        }
    }
}

// ---------------------------------------------------------------------------
// Fallback (no workspace) — kept for safety.
// ---------------------------------------------------------------------------
static __device__ __forceinline__ int swz(int row, int k) {
    int byte = (row << 7) + (k << 1);
    byte ^= (row & 7) << 4;
    return byte >> 1;
}

__global__ __launch_bounds__(256, 2) void lstm_fallback_kernel(
    const float* __restrict__ x, const float* __restrict__ hprev,
    const float* __restrict__ cprev, const float* __restrict__ Wx,
    const float* __restrict__ Wh, const float* __restrict__ bh,
    float* __restrict__ out)
{
    __shared__ __align__(16) short As[128 * 64];
    __shared__ __align__(16) short Bs[128 * 64];

    int bid = blockIdx.x;
    bid = (bid & 7) * 256 + (bid >> 3);
    const int mt = bid >> 5;
    const int ht = bid & 31;
    const int m0 = mt * 128;
    const int h0 = ht * 32;

    const int t    = threadIdx.x;
    const int lane = t & 63;
    const int w    = t >> 6;
    const int wr   = w >> 1;
    const int wc   = w & 1;

    const int srow = t >> 3;
    const int sk   = (t & 7) * 8;

    f32x4 acc[4][4] = {};

    #pragma unroll 1
    for (int phase = 0; phase < 2; ++phase) {
        const float* __restrict__ Ap = phase ? hprev : x;
        const float* __restrict__ Bp = phase ? Wh : Wx;
        #pragma unroll 1
        for (int kk = 0; kk < 1024; kk += 64) {
            __syncthreads();
            #pragma unroll
            for (int p = 0; p < 4; ++p) {
                const int row = srow + p * 32;
                const float4* src = (const float4*)(Ap + (size_t)(m0 + row) * I_DIM + kk + sk);
                *(short8*)&As[swz(row, sk)] = pack8(src[0], src[1]);
            }
            #pragma unroll
            for (int p = 0; p < 4; ++p) {
                const int n    = srow + p * 32;
                const int gate = (n >> 4) & 3;
                const int hcol = h0 + ((n >> 6) << 4) + (n & 15);
                const float4* src = (const float4*)(Bp + (size_t)((gate << 10) + hcol) * 1024 + kk + sk);
                *(short8*)&Bs[swz(n, sk)] = pack8(src[0], src[1]);
            }
            __syncthreads();
            #pragma unroll
            for (int ks = 0; ks < 2; ++ks) {
                const int kb = ks * 32 + ((lane >> 4) << 3);
                short8 a[4], b[4];
                #pragma unroll
                for (int m = 0; m < 4; ++m)
                    a[m] = *(const short8*)&As[swz(wr * 64 + m * 16 + (lane & 15), kb)];
                #pragma unroll
                for (int j = 0; j < 4; ++j)
                    b[j] = *(const short8*)&Bs[swz(wc * 64 + j * 16 + (lane & 15), kb)];
                #pragma unroll
                for (int m = 0; m < 4; ++m)
                    #pragma unroll
                    for (int j = 0; j < 4; ++j)
                        acc[m][j] = __builtin_amdgcn_mfma_f32_16x16x32_bf16(a[m], b[j], acc[m][j], 0, 0, 0);
            }
        }
    }

    const int cl = lane & 15;
    const int rg = lane >> 4;
    const int h  = h0 + wc * 16 + cl;
    const float b_i = bh[0 * H_DIM + h];
    const float b_f = bh[1 * H_DIM + h];
    const float b_g = bh[2 * H_DIM + h];
    const float b_o = bh[3 * H_DIM + h];

    #pragma unroll
    for (int m = 0; m < 4; ++m) {
        #pragma unroll
        for (int r = 0; r < 4; ++r) {
            const int row = m0 + wr * 64 + m * 16 + rg * 4 + r;
            const float pi = acc[m][0][r] + b_i;
            const float pf = acc[m][1][r] + b_f;
            const float pg = acc[m][2][r] + b_g;
            const float po = acc[m][3][r] + b_o;
            const float iv = sigmoid_f(pi);
            const float fv = sigmoid_f(pf);
            const float gv = tanh_fast(pg);
            const float ov = sigmoid_f(po);
            const float cp = cprev[(size_t)row * H_DIM + h];
            const float cn = fv * cp + iv * gv;
            const float hn = ov * tanh_fast(cn);
            out[(size_t)row * H_DIM + h] = hn;
            out[(size_t)B_DIM * H_DIM + (size_t)row * H_DIM + h] = cn;
        }
    }
}

extern "C" void kernel_launch(void* const* d_in, const int* in_sizes, int n_in,
                              void* d_out, int out_size, void* d_ws, size_t ws_size,
                              hipStream_t stream) {
    const float* x     = (const float*)d_in[0];
    const float* hprev = (const float*)d_in[1];
    const float* cprev = (const float*)d_in[2];
    const float* Wx    = (const float*)d_in[3];
    const float* Wh    = (const float*)d_in[4];
    const float* bh    = (const float*)d_in[5];
    float* out = (float*)d_out;

    const size_t need = ((size_t)B_DIM * 2048 + (size_t)4096 * 2048) * sizeof(short);
    if (ws_size >= need && d_ws != nullptr) {
        short* Aw = (short*)d_ws;                 // A_fw: 512 frags * 32768 shorts
        short* Bw = Aw + (size_t)512 * 32768;     // B_fw: 256 frags * 32768 shorts
        hipLaunchKernelGGL(convert_kernel, dim3(4096), dim3(256), 0, stream,
                           x, hprev, Wx, Wh, Aw, Bw);
        hipLaunchKernelGGL(lstm_gemm_cnt_kernel, dim3(2048), dim3(256), 0, stream,
                           Aw, Bw, cprev, bh, out);
    } else {
        hipLaunchKernelGGL(lstm_fallback_kernel, dim3(2048), dim3(256), 0, stream,
                           x, hprev, cprev, Wx, Wh, bh, out);
    }
}

// Round 12
// 150.116 us; speedup vs baseline: 1.0929x; 1.0087x over previous
//
#include <hip/hip_runtime.h>
#include <hip/hip_bf16.h>
#include <stdint.h>

#define B_DIM 8192
#define I_DIM 1024
#define H_DIM 1024

typedef __attribute__((ext_vector_type(8))) short short8;
typedef __attribute__((ext_vector_type(4))) float f32x4;

static __device__ __forceinline__ short f2b(float f) {
    __bf16 h = (__bf16)f;
    return __builtin_bit_cast(short, h);
}

static __device__ __forceinline__ short8 pack8(float4 a, float4 b) {
    short8 s;
    s[0] = f2b(a.x); s[1] = f2b(a.y); s[2] = f2b(a.z); s[3] = f2b(a.w);
    s[4] = f2b(b.x); s[5] = f2b(b.y); s[6] = f2b(b.z); s[7] = f2b(b.w);
    return s;
}

static __device__ __forceinline__ float sigmoid_f(float x) {
    return 1.0f / (1.0f + __expf(-x));
}

static __device__ __forceinline__ float tanh_fast(float x) {
    x = fminf(fmaxf(x, -15.0f), 15.0f);
    float e = __expf(2.0f * x);
    return (e - 1.0f) / (e + 1.0f);
}

static __device__ __forceinline__ void load_lds16(const void* gptr, void* lptr) {
    __builtin_amdgcn_global_load_lds(
        (const __attribute__((address_space(1))) uint32_t*)gptr,
        (__attribute__((address_space(3))) uint32_t*)lptr, 16, 0, 0);
}

// ---------------------------------------------------------------------------
// Pass 1: fp32 -> bf16 conversion into FRAGMENT-ORDERED workspace (unchanged).
//   A_fw: [mfrag 0..511][k32 0..63][lane 0..63][8 bf16]
//         row = mfrag*16 + (lane&15), k = k32*32 + (lane>>4)*8
//   B_fw: [nfrag 0..255][k32][lane][8]
//         nfrag = bn*16 + cf; gate = cf&3; col = bn*64 + (cf>>2)*16 + (lane&15)
//         (equivalently nfrag = nt*8 + wn*4 + gate with nt = 32-h tile)
// ---------------------------------------------------------------------------
#define GA_GROUPS (512 * 32 * 2 * 64)   // 2,097,152  (A 16B-groups)
#define GB_GROUPS (256 * 32 * 2 * 64)   // 1,048,576  (B 16B-groups)

__global__ __launch_bounds__(256) void convert_kernel(
    const float* __restrict__ x, const float* __restrict__ h,
    const float* __restrict__ wx, const float* __restrict__ wh,
    short* __restrict__ Aw, short* __restrict__ Bw)
{
    const int64_t total = (int64_t)GA_GROUPS + GB_GROUPS;
    for (int64_t g = (int64_t)blockIdx.x * blockDim.x + threadIdx.x; g < total;
         g += (int64_t)gridDim.x * blockDim.x) {
        const float* src;
        short* dst;
        if (g < GA_GROUPS) {
            const int lane = (int)(g & 63);
            const int rest = (int)(g >> 6);
            const int kh   = rest & 1;
            const int tk   = (rest >> 1) & 31;
            const int mfrag = rest >> 6;
            const int row = (mfrag << 4) + (lane & 15);
            const int k   = (tk << 6) + (kh << 5) + ((lane >> 4) << 3);
            src = (k < 1024) ? (x + (size_t)row * 1024 + k)
                             : (h + (size_t)row * 1024 + (k - 1024));
            dst = Aw + (size_t)g * 8;
        } else {
            const int64_t gb = g - GA_GROUPS;
            const int lane = (int)(gb & 63);
            const int rest = (int)(gb >> 6);
            const int kh   = rest & 1;
            const int tk   = (rest >> 1) & 31;
            const int nfrag = rest >> 6;
            const int cf   = nfrag & 15;
            const int bn   = nfrag >> 4;
            const int gate = cf & 3;
            const int col  = (bn << 6) + ((cf >> 2) << 4) + (lane & 15);
            const int k    = (tk << 6) + (kh << 5) + ((lane >> 4) << 3);
            src = (k < 1024) ? (wx + ((size_t)(gate << 10) + col) * 1024 + k)
                             : (wh + ((size_t)(gate << 10) + col) * 1024 + (k - 1024));
            dst = Bw + (size_t)gb * 8;
        }
        float4 v0 = ((const float4*)src)[0];
        float4 v1 = ((const float4*)src)[1];
        *(short8*)dst = pack8(v0, v1);
    }
}

// ---------------------------------------------------------------------------
// Pass 2: 256x128-tile GEMM, BK=32, 4 waves, wave-tile 128x64 (acc[8][4]).
// DOUBLED ARITHMETIC INTENSITY PER LDS BYTE (29 vs 21 FLOP/LDS-byte) — LDS
// unit was the binding resource at 61-92% utilization in R11.
// Counted-vmcnt pipeline kept: 3 rotating LDS buffers (72 KiB dynamic ->
// 2 blocks/CU), stage issued 2 tiles ahead, per-tile
// "vmcnt(6) -> barrier -> stage(t+2) -> ds_read buf[t%3] -> 32 MFMA".
// Fragment-ordered workspace (contiguous 1 KiB gload_lds), fragment-tile LDS
// (0 bank conflicts). Fused in-register LSTM epilogue.
// LDS: [3 buf][16 A-frags | 8 B-frags][512 shorts] = 72 KiB.
// ---------------------------------------------------------------------------
#define AOFF(d, f) ((d) * 12288 + (f) * 512)
#define BOFF(d, f) ((d) * 12288 + 8192 + (f) * 512)

__global__ __launch_bounds__(256, 2) void lstm_gemm_big_kernel(
    const short* __restrict__ Aw, const short* __restrict__ Bw,
    const float* __restrict__ cprev, const float* __restrict__ bh,
    float* __restrict__ out)
{
    extern __shared__ __align__(16) short smem[];   // 72 KiB dynamic

    // XCD-aware: hw round-robins blockIdx -> XCD (xcd = bid&7). Each XCD works
    // nt in {4*xcd .. 4*xcd+3} (its ~2 MB B-slice L2-resident); 4 consecutive
    // same-XCD blocks share one A-panel (c>>2 = bm) for A L2 locality.
    const int bid = blockIdx.x;
    const int xcd = bid & 7;
    const int c   = bid >> 3;            // 0..127 within XCD
    const int bm  = c >> 2;              // 0..31  (256-row M tile)
    const int nt  = 4 * xcd + (c & 3);   // 0..31  (32-h N tile)
    const int m0  = bm * 256;

    const int t    = threadIdx.x;
    const int lane = t & 63;
    const int w    = t >> 6;     // wave 0..3
    const int wm   = w >> 1;     // 0..1  M half (128 rows)
    const int wn   = w & 1;      // 0..1  N half (16-h group)
    const int lc   = lane & 15;

    // staging sources (contiguous 1 KiB per gload_lds): wave w stages A-frags
    // 4w..4w+3 and B-frags 2w,2w+1. Frag stride = 64 k32-tiles * 512 shorts.
    const short* aSrc0 = Aw + (size_t)(bm * 16 + 4 * w + 0) * 32768 + lane * 8;
    const short* aSrc1 = Aw + (size_t)(bm * 16 + 4 * w + 1) * 32768 + lane * 8;
    const short* aSrc2 = Aw + (size_t)(bm * 16 + 4 * w + 2) * 32768 + lane * 8;
    const short* aSrc3 = Aw + (size_t)(bm * 16 + 4 * w + 3) * 32768 + lane * 8;
    const short* bSrc0 = Bw + (size_t)(nt * 8 + 2 * w)     * 32768 + lane * 8;
    const short* bSrc1 = Bw + (size_t)(nt * 8 + 2 * w + 1) * 32768 + lane * 8;

    f32x4 acc[8][4] = {};   // [m-frag][gate]

#define STAGE(db, tp) \
    load_lds16(aSrc0 + (tp) * 512, &smem[AOFF(db, 4 * w + 0)]); \
    load_lds16(aSrc1 + (tp) * 512, &smem[AOFF(db, 4 * w + 1)]); \
    load_lds16(aSrc2 + (tp) * 512, &smem[AOFF(db, 4 * w + 2)]); \
    load_lds16(aSrc3 + (tp) * 512, &smem[AOFF(db, 4 * w + 3)]); \
    load_lds16(bSrc0 + (tp) * 512, &smem[BOFF(db, 2 * w)]); \
    load_lds16(bSrc1 + (tp) * 512, &smem[BOFF(db, 2 * w + 1)]);

// One k32-tile: wait only for the stage issued two tiles ago (6 newest loads
// = next tile's stage, left in flight), barrier, issue stage 2 ahead, read
// current buffer, 32 MFMA (A in two 4-frag halves to bound live registers).
#define TILE(db, sdb, tp) do { \
    asm volatile("s_waitcnt vmcnt(6)" ::: "memory"); \
    __builtin_amdgcn_s_barrier(); \
    STAGE(sdb, tp) \
    short8 bv[4]; \
    _Pragma("unroll") \
    for (int j = 0; j < 4; ++j) \
        bv[j] = *(const short8*)&smem[BOFF(db, wn * 4 + j) + lane * 8]; \
    short8 av0[4]; \
    _Pragma("unroll") \
    for (int i = 0; i < 4; ++i) \
        av0[i] = *(const short8*)&smem[AOFF(db, wm * 8 + i) + lane * 8]; \
    __builtin_amdgcn_s_setprio(1); \
    _Pragma("unroll") \
    for (int i = 0; i < 4; ++i) \
        _Pragma("unroll") \
        for (int j = 0; j < 4; ++j) \
            acc[i][j] = __builtin_amdgcn_mfma_f32_16x16x32_bf16( \
                av0[i], bv[j], acc[i][j], 0, 0, 0); \
    __builtin_amdgcn_s_setprio(0); \
    short8 av1[4]; \
    _Pragma("unroll") \
    for (int i = 0; i < 4; ++i) \
        av1[i] = *(const short8*)&smem[AOFF(db, wm * 8 + 4 + i) + lane * 8]; \
    __builtin_amdgcn_s_setprio(1); \
    _Pragma("unroll") \
    for (int i = 0; i < 4; ++i) \
        _Pragma("unroll") \
        for (int j = 0; j < 4; ++j) \
            acc[4 + i][j] = __builtin_amdgcn_mfma_f32_16x16x32_bf16( \
                av1[i], bv[j], acc[4 + i][j], 0, 0, 0); \
    __builtin_amdgcn_s_setprio(0); \
} while (0)

    // prologue: stage tiles 0,1 into bufs 0,1 (12 loads outstanding)
    STAGE(0, 0)
    STAGE(1, 1)

    // tiles 0..62 in triples (compile-time buffer index), tile 63 separate
    #pragma unroll 1
    for (int tk3 = 0; tk3 < 21; ++tk3) {
        const int t0 = 3 * tk3;
        const int p2 = (t0 + 2 < 64) ? t0 + 2 : 63;
        const int p3 = (t0 + 3 < 64) ? t0 + 3 : 63;
        const int p4 = (t0 + 4 < 64) ? t0 + 4 : 63;
        TILE(0, 2, p2);
        TILE(1, 0, p3);
        TILE(2, 1, p4);
    }
    TILE(0, 2, 63);   // tile 63 reads buf 0 (staged at t=61); dummy stage
#undef TILE
#undef STAGE
    asm volatile("s_waitcnt vmcnt(0)" ::: "memory");

    // ---- fused LSTM epilogue, in-register ----
    // D layout: col = lane&15 (h), row = (lane>>4)*4 + reg
    const int rg = lane >> 4;
    const int h  = nt * 32 + wn * 16 + lc;
    const float b_i = bh[0 * H_DIM + h];
    const float b_f = bh[1 * H_DIM + h];
    const float b_g = bh[2 * H_DIM + h];
    const float b_o = bh[3 * H_DIM + h];

    #pragma unroll
    for (int mf = 0; mf < 8; ++mf) {
        #pragma unroll
        for (int r = 0; r < 4; ++r) {
            const int row = m0 + wm * 128 + mf * 16 + rg * 4 + r;
            const float pi = acc[mf][0][r] + b_i;
            const float pf = acc[mf][1][r] + b_f;
            const float pg = acc[mf][2][r] + b_g;
            const float po = acc[mf][3][r] + b_o;
            const float iv = sigmoid_f(pi);
            const float fv = sigmoid_f(pf);
            const float gv = tanh_fast(pg);
            const float ov = sigmoid_f(po);
            const float cp = cprev[(size_t)row * H_DIM + h];
            const float cn = fv * cp + iv * gv;
            const float hn = ov * tanh_fast(cn);
            out[(size_t)row * H_DIM + h] = hn;
            out[(size_t)B_DIM * H_DIM + (size_t)row * H_DIM + h] = cn;
        }
    }
}

// ---------------------------------------------------------------------------
// Fallback (no workspace) — kept for safety.
// ---------------------------------------------------------------------------
static __device__ __forceinline__ int swz(int row, int k) {
    int byte = (row << 7) + (k << 1);
    byte ^= (row & 7) << 4;
    return byte >> 1;
}

__global__ __launch_bounds__(256, 2) void lstm_fallback_kernel(
    const float* __restrict__ x, const float* __restrict__ hprev,
    const float* __restrict__ cprev, const float* __restrict__ Wx,
    const float* __restrict__ Wh, const float* __restrict__ bh,
    float* __restrict__ out)
{
    __shared__ __align__(16) short As[128 * 64];
    __shared__ __align__(16) short Bs[128 * 64];

    int bid = blockIdx.x;
    bid = (bid & 7) * 256 + (bid >> 3);
    const int mt = bid >> 5;
    const int ht = bid & 31;
    const int m0 = mt * 128;
    const int h0 = ht * 32;

    const int t    = threadIdx.x;
    const int lane = t & 63;
    const int w    = t >> 6;
    const int wr   = w >> 1;
    const int wc   = w & 1;

    const int srow = t >> 3;
    const int sk   = (t & 7) * 8;

    f32x4 acc[4][4] = {};

    #pragma unroll 1
    for (int phase = 0; phase < 2; ++phase) {
        const float* __restrict__ Ap = phase ? hprev : x;
        const float* __restrict__ Bp = phase ? Wh : Wx;
        #pragma unroll 1
        for (int kk = 0; kk < 1024; kk += 64) {
            __syncthreads();
            #pragma unroll
            for (int p = 0; p < 4; ++p) {
                const int row = srow + p * 32;
                const float4* src = (const float4*)(Ap + (size_t)(m0 + row) * I_DIM + kk + sk);
                *(short8*)&As[swz(row, sk)] = pack8(src[0], src[1]);
            }
            #pragma unroll
            for (int p = 0; p < 4; ++p) {
                const int n    = srow + p * 32;
                const int gate = (n >> 4) & 3;
                const int hcol = h0 + ((n >> 6) << 4) + (n & 15);
                const float4* src = (const float4*)(Bp + (size_t)((gate << 10) + hcol) * 1024 + kk + sk);
                *(short8*)&Bs[swz(n, sk)] = pack8(src[0], src[1]);
            }
            __syncthreads();
            #pragma unroll
            for (int ks = 0; ks < 2; ++ks) {
                const int kb = ks * 32 + ((lane >> 4) << 3);
                short8 a[4], b[4];
                #pragma unroll
                for (int m = 0; m < 4; ++m)
                    a[m] = *(const short8*)&As[swz(wr * 64 + m * 16 + (lane & 15), kb)];
                #pragma unroll
                for (int j = 0; j < 4; ++j)
                    b[j] = *(const short8*)&Bs[swz(wc * 64 + j * 16 + (lane & 15), kb)];
                #pragma unroll
                for (int m = 0; m < 4; ++m)
                    #pragma unroll
                    for (int j = 0; j < 4; ++j)
                        acc[m][j] = __builtin_amdgcn_mfma_f32_16x16x32_bf16(a[m], b[j], acc[m][j], 0, 0, 0);
            }
        }
    }

    const int cl = lane & 15;
    const int rg = lane >> 4;
    const int h  = h0 + wc * 16 + cl;
    const float b_i = bh[0 * H_DIM + h];
    const float b_f = bh[1 * H_DIM + h];
    const float b_g = bh[2 * H_DIM + h];
    const float b_o = bh[3 * H_DIM + h];

    #pragma unroll
    for (int m = 0; m < 4; ++m) {
        #pragma unroll
        for (int r = 0; r < 4; ++r) {
            const int row = m0 + wr * 64 + m * 16 + rg * 4 + r;
            const float pi = acc[m][0][r] + b_i;
            const float pf = acc[m][1][r] + b_f;
            const float pg = acc[m][2][r] + b_g;
            const float po = acc[m][3][r] + b_o;
            const float iv = sigmoid_f(pi);
            const float fv = sigmoid_f(pf);
            const float gv = tanh_fast(pg);
            const float ov = sigmoid_f(po);
            const float cp = cprev[(size_t)row * H_DIM + h];
            const float cn = fv * cp + iv * gv;
            const float hn = ov * tanh_fast(cn);
            out[(size_t)row * H_DIM + h] = hn;
            out[(size_t)B_DIM * H_DIM + (size_t)row * H_DIM + h] = cn;
        }
    }
}

extern "C" void kernel_launch(void* const* d_in, const int* in_sizes, int n_in,
                              void* d_out, int out_size, void* d_ws, size_t ws_size,
                              hipStream_t stream) {
    const float* x     = (const float*)d_in[0];
    const float* hprev = (const float*)d_in[1];
    const float* cprev = (const float*)d_in[2];
    const float* Wx    = (const float*)d_in[3];
    const float* Wh    = (const float*)d_in[4];
    const float* bh    = (const float*)d_in[5];
    float* out = (float*)d_out;

    const size_t need = ((size_t)B_DIM * 2048 + (size_t)4096 * 2048) * sizeof(short);
    if (ws_size >= need && d_ws != nullptr) {
        (void)hipFuncSetAttribute((const void*)lstm_gemm_big_kernel,
                                  hipFuncAttributeMaxDynamicSharedMemorySize, 73728);
        short* Aw = (short*)d_ws;                 // A_fw: 512 frags * 32768 shorts
        short* Bw = Aw + (size_t)512 * 32768;     // B_fw: 256 frags * 32768 shorts
        hipLaunchKernelGGL(convert_kernel, dim3(4096), dim3(256), 0, stream,
                           x, hprev, Wx, Wh, Aw, Bw);
        hipLaunchKernelGGL(lstm_gemm_big_kernel, dim3(1024), dim3(256), 73728, stream,
                           Aw, Bw, cprev, bh, out);
    } else {
        hipLaunchKernelGGL(lstm_fallback_kernel, dim3(2048), dim3(256), 0, stream,
                           x, hprev, cprev, Wx, Wh, bh, out);
    }
}

// Round 13
// 149.882 us; speedup vs baseline: 1.0946x; 1.0016x over previous
//
#include <hip/hip_runtime.h>
#include <hip/hip_bf16.h>
#include <stdint.h>

#define B_DIM 8192
#define I_DIM 1024
#define H_DIM 1024

typedef __attribute__((ext_vector_type(8))) short short8;
typedef __attribute__((ext_vector_type(4))) float f32x4;

static __device__ __forceinline__ short f2b(float f) {
    __bf16 h = (__bf16)f;
    return __builtin_bit_cast(short, h);
}

static __device__ __forceinline__ short8 pack8(float4 a, float4 b) {
    short8 s;
    s[0] = f2b(a.x); s[1] = f2b(a.y); s[2] = f2b(a.z); s[3] = f2b(a.w);
    s[4] = f2b(b.x); s[5] = f2b(b.y); s[6] = f2b(b.z); s[7] = f2b(b.w);
    return s;
}

static __device__ __forceinline__ float sigmoid_f(float x) {
    return 1.0f / (1.0f + __expf(-x));
}

static __device__ __forceinline__ float tanh_fast(float x) {
    x = fminf(fmaxf(x, -15.0f), 15.0f);
    float e = __expf(2.0f * x);
    return (e - 1.0f) / (e + 1.0f);
}

static __device__ __forceinline__ void load_lds16(const void* gptr, void* lptr) {
    __builtin_amdgcn_global_load_lds(
        (const __attribute__((address_space(1))) uint32_t*)gptr,
        (__attribute__((address_space(3))) uint32_t*)lptr, 16, 0, 0);
}

// ---------------------------------------------------------------------------
// Pass 1: fp32 -> bf16 conversion into FRAGMENT-ORDERED workspace (unchanged).
//   A_fw: [mfrag 0..511][k32 0..63][lane 0..63][8 bf16]
//         row = mfrag*16 + (lane&15), k = k32*32 + (lane>>4)*8
//   B_fw: [nfrag 0..255][k32][lane][8]
//         nfrag = bn*16 + cf; gate = cf&3; col = bn*64 + (cf>>2)*16 + (lane&15)
// ---------------------------------------------------------------------------
#define GA_GROUPS (512 * 32 * 2 * 64)   // 2,097,152  (A 16B-groups)
#define GB_GROUPS (256 * 32 * 2 * 64)   // 1,048,576  (B 16B-groups)

__global__ __launch_bounds__(256) void convert_kernel(
    const float* __restrict__ x, const float* __restrict__ h,
    const float* __restrict__ wx, const float* __restrict__ wh,
    short* __restrict__ Aw, short* __restrict__ Bw)
{
    const int64_t total = (int64_t)GA_GROUPS + GB_GROUPS;
    for (int64_t g = (int64_t)blockIdx.x * blockDim.x + threadIdx.x; g < total;
         g += (int64_t)gridDim.x * blockDim.x) {
        const float* src;
        short* dst;
        if (g < GA_GROUPS) {
            const int lane = (int)(g & 63);
            const int rest = (int)(g >> 6);
            const int kh   = rest & 1;
            const int tk   = (rest >> 1) & 31;
            const int mfrag = rest >> 6;
            const int row = (mfrag << 4) + (lane & 15);
            const int k   = (tk << 6) + (kh << 5) + ((lane >> 4) << 3);
            src = (k < 1024) ? (x + (size_t)row * 1024 + k)
                             : (h + (size_t)row * 1024 + (k - 1024));
            dst = Aw + (size_t)g * 8;
        } else {
            const int64_t gb = g - GA_GROUPS;
            const int lane = (int)(gb & 63);
            const int rest = (int)(gb >> 6);
            const int kh   = rest & 1;
            const int tk   = (rest >> 1) & 31;
            const int nfrag = rest >> 6;
            const int cf   = nfrag & 15;
            const int bn   = nfrag >> 4;
            const int gate = cf & 3;
            const int col  = (bn << 6) + ((cf >> 2) << 4) + (lane & 15);
            const int k    = (tk << 6) + (kh << 5) + ((lane >> 4) << 3);
            src = (k < 1024) ? (wx + ((size_t)(gate << 10) + col) * 1024 + k)
                             : (wh + ((size_t)(gate << 10) + col) * 1024 + (k - 1024));
            dst = Bw + (size_t)gb * 8;
        }
        float4 v0 = ((const float4*)src)[0];
        float4 v1 = ((const float4*)src)[1];
        *(short8*)dst = pack8(v0, v1);
    }
}

// ---------------------------------------------------------------------------
// Pass 2: m201-style 8-phase GEMM. 256x256 tile (256 rows x 4 gates x 64 h),
// 512 threads = 8 waves (2M x 4N), per-wave 128x64, acc[8][4].
// Ring of 4 k32 LDS buffers (32 KiB each = 128 KiB, 1 block/CU).
// Per k32-step: 2 phases {ds_read quadrant + 2 stage-gloads -> barrier ->
// setprio + 16 MFMA -> barrier}; B read ONCE per k32, register-reused across
// both m-halves; stage issued 3 steps ahead; vmcnt(8) once per step (waits
// only for loads issued ~3 steps earlier — deep counted prefetch, R11-proven).
// Fragment-ordered workspace (contiguous 1 KiB gloads), fragment-tile LDS
// (0 bank conflicts). Fused in-register LSTM epilogue.
// ---------------------------------------------------------------------------
#define AOFF(r, f) ((r) * 16384 + (f) * 512)
#define BOFF(r, f) ((r) * 16384 + 8192 + (f) * 512)

__global__ __launch_bounds__(512, 2) void lstm_gemm_p8_kernel(
    const short* __restrict__ Aw, const short* __restrict__ Bw,
    const float* __restrict__ cprev, const float* __restrict__ bh,
    float* __restrict__ out)
{
    extern __shared__ __align__(16) short smem[];   // 128 KiB dynamic

    // XCD-aware bijective swizzle: 512 blocks, 8 XCDs. Same-XCD consecutive
    // blocks share bm (A-panel L2 locality).
    int bid = blockIdx.x;
    bid = (bid & 7) * 64 + (bid >> 3);
    const int bm = bid >> 4;     // 0..31  (256-row M tile)
    const int bn = bid & 15;     // 0..15  (64-h N tile)
    const int m0 = bm * 256;
    const int h0 = bn * 64;

    const int t    = threadIdx.x;
    const int lane = t & 63;
    const int w    = t >> 6;     // wave 0..7
    const int wm   = w >> 2;     // 0..1  M half (128 rows)
    const int wn   = w & 3;      // 0..3  N quarter (16-h group)
    const int lc   = lane & 15;

    // staging sources: wave w stages A-frags {2w,2w+1} and B-frags {2w,2w+1}.
    // Frag stride = 64 k32-tiles * 512 shorts = 32768.
    const short* aSrc0 = Aw + (size_t)(bm * 16 + 2 * w)     * 32768 + lane * 8;
    const short* aSrc1 = Aw + (size_t)(bm * 16 + 2 * w + 1) * 32768 + lane * 8;
    const short* bSrc0 = Bw + (size_t)(bn * 16 + 2 * w)     * 32768 + lane * 8;
    const short* bSrc1 = Bw + (size_t)(bn * 16 + 2 * w + 1) * 32768 + lane * 8;

    f32x4 acc[8][4] = {};   // [m-frag][gate]

#define SA(r, p) \
    load_lds16(aSrc0 + (p) * 512, &smem[AOFF(r, 2 * w)]); \
    load_lds16(aSrc1 + (p) * 512, &smem[AOFF(r, 2 * w + 1)]);
#define SB(r, p) \
    load_lds16(bSrc0 + (p) * 512, &smem[BOFF(r, 2 * w)]); \
    load_lds16(bSrc1 + (p) * 512, &smem[BOFF(r, 2 * w + 1)]);

// One k32-step on ring buffer r, staging k32 p into ring buffer pr.
// Phase A: read B(4) + A-low(4), stage A-part, barrier, 16 MFMA, barrier.
// Phase B: read A-high(4) (B reused in regs), stage B-part, barrier, 16 MFMA,
//          vmcnt(8) [waits only for the stage issued 3 steps ago], barrier.
#define STEP(r, pr, p) do { \
    short8 bv[4], av[4]; \
    _Pragma("unroll") \
    for (int j = 0; j < 4; ++j) \
        bv[j] = *(const short8*)&smem[BOFF(r, wn * 4 + j) + lane * 8]; \
    _Pragma("unroll") \
    for (int i = 0; i < 4; ++i) \
        av[i] = *(const short8*)&smem[AOFF(r, wm * 8 + i) + lane * 8]; \
    SA(pr, p) \
    __builtin_amdgcn_s_barrier(); \
    __builtin_amdgcn_s_setprio(1); \
    _Pragma("unroll") \
    for (int i = 0; i < 4; ++i) \
        _Pragma("unroll") \
        for (int j = 0; j < 4; ++j) \
            acc[i][j] = __builtin_amdgcn_mfma_f32_16x16x32_bf16( \
                av[i], bv[j], acc[i][j], 0, 0, 0); \
    __builtin_amdgcn_s_setprio(0); \
    __builtin_amdgcn_s_barrier(); \
    short8 aw[4]; \
    _Pragma("unroll") \
    for (int i = 0; i < 4; ++i) \
        aw[i] = *(const short8*)&smem[AOFF(r, wm * 8 + 4 + i) + lane * 8]; \
    SB(pr, p) \
    __builtin_amdgcn_s_barrier(); \
    __builtin_amdgcn_s_setprio(1); \
    _Pragma("unroll") \
    for (int i = 0; i < 4; ++i) \
        _Pragma("unroll") \
        for (int j = 0; j < 4; ++j) \
            acc[4 + i][j] = __builtin_amdgcn_mfma_f32_16x16x32_bf16( \
                aw[i], bv[j], acc[4 + i][j], 0, 0, 0); \
    __builtin_amdgcn_s_setprio(0); \
    asm volatile("s_waitcnt vmcnt(8)" ::: "memory"); \
    __builtin_amdgcn_s_barrier(); \
} while (0)

    // prologue: stage k32 0,1,2 into ring bufs 0,1,2 (12 loads/wave in flight);
    // vmcnt(8) -> own k32-0 stage done; barrier -> all waves' stages visible.
    SA(0, 0) SB(0, 0)
    SA(1, 1) SB(1, 1)
    SA(2, 2) SB(2, 2)
    asm volatile("s_waitcnt vmcnt(8)" ::: "memory");
    __builtin_amdgcn_s_barrier();

    #pragma unroll 1
    for (int s4 = 0; s4 < 16; ++s4) {
        const int b4 = 4 * s4;
        const int p0 = (b4 + 3 < 64) ? b4 + 3 : 63;
        const int p1 = (b4 + 4 < 64) ? b4 + 4 : 63;
        const int p2 = (b4 + 5 < 64) ? b4 + 5 : 63;
        const int p3 = (b4 + 6 < 64) ? b4 + 6 : 63;
        STEP(0, 3, p0);
        STEP(1, 0, p1);
        STEP(2, 1, p2);
        STEP(3, 2, p3);
    }
#undef STEP
#undef SA
#undef SB
    asm volatile("s_waitcnt vmcnt(0)" ::: "memory");

    // ---- fused LSTM epilogue, in-register ----
    // D layout: col = lane&15 (h), row = (lane>>4)*4 + reg
    const int rg = lane >> 4;
    const int h  = h0 + wn * 16 + lc;
    const float b_i = bh[0 * H_DIM + h];
    const float b_f = bh[1 * H_DIM + h];
    const float b_g = bh[2 * H_DIM + h];
    const float b_o = bh[3 * H_DIM + h];

    #pragma unroll
    for (int mf = 0; mf < 8; ++mf) {
        #pragma unroll
        for (int r = 0; r < 4; ++r) {
            const int row = m0 + wm * 128 + mf * 16 + rg * 4 + r;
            const float pi = acc[mf][0][r] + b_i;
            const float pf = acc[mf][1][r] + b_f;
            const float pg = acc[mf][2][r] + b_g;
            const float po = acc[mf][3][r] + b_o;
            const float iv = sigmoid_f(pi);
            const float fv = sigmoid_f(pf);
            const float gv = tanh_fast(pg);
            const float ov = sigmoid_f(po);
            const float cp = cprev[(size_t)row * H_DIM + h];
            const float cn = fv * cp + iv * gv;
            const float hn = ov * tanh_fast(cn);
            out[(size_t)row * H_DIM + h] = hn;
            out[(size_t)B_DIM * H_DIM + (size_t)row * H_DIM + h] = cn;
        }
    }
}

// ---------------------------------------------------------------------------
// Fallback (no workspace) — kept for safety.
// ---------------------------------------------------------------------------
static __device__ __forceinline__ int swz(int row, int k) {
    int byte = (row << 7) + (k << 1);
    byte ^= (row & 7) << 4;
    return byte >> 1;
}

__global__ __launch_bounds__(256, 2) void lstm_fallback_kernel(
    const float* __restrict__ x, const float* __restrict__ hprev,
    const float* __restrict__ cprev, const float* __restrict__ Wx,
    const float* __restrict__ Wh, const float* __restrict__ bh,
    float* __restrict__ out)
{
    __shared__ __align__(16) short As[128 * 64];
    __shared__ __align__(16) short Bs[128 * 64];

    int bid = blockIdx.x;
    bid = (bid & 7) * 256 + (bid >> 3);
    const int mt = bid >> 5;
    const int ht = bid & 31;
    const int m0 = mt * 128;
    const int h0 = ht * 32;

    const int t    = threadIdx.x;
    const int lane = t & 63;
    const int w    = t >> 6;
    const int wr   = w >> 1;
    const int wc   = w & 1;

    const int srow = t >> 3;
    const int sk   = (t & 7) * 8;

    f32x4 acc[4][4] = {};

    #pragma unroll 1
    for (int phase = 0; phase < 2; ++phase) {
        const float* __restrict__ Ap = phase ? hprev : x;
        const float* __restrict__ Bp = phase ? Wh : Wx;
        #pragma unroll 1
        for (int kk = 0; kk < 1024; kk += 64) {
            __syncthreads();
            #pragma unroll
            for (int p = 0; p < 4; ++p) {
                const int row = srow + p * 32;
                const float4* src = (const float4*)(Ap + (size_t)(m0 + row) * I_DIM + kk + sk);
                *(short8*)&As[swz(row, sk)] = pack8(src[0], src[1]);
            }
            #pragma unroll
            for (int p = 0; p < 4; ++p) {
                const int n    = srow + p * 32;
                const int gate = (n >> 4) & 3;
                const int hcol = h0 + ((n >> 6) << 4) + (n & 15);
                const float4* src = (const float4*)(Bp + (size_t)((gate << 10) + hcol) * 1024 + kk + sk);
                *(short8*)&Bs[swz(n, sk)] = pack8(src[0], src[1]);
            }
            __syncthreads();
            #pragma unroll
            for (int ks = 0; ks < 2; ++ks) {
                const int kb = ks * 32 + ((lane >> 4) << 3);
                short8 a[4], b[4];
                #pragma unroll
                for (int m = 0; m < 4; ++m)
                    a[m] = *(const short8*)&As[swz(wr * 64 + m * 16 + (lane & 15), kb)];
                #pragma unroll
                for (int j = 0; j < 4; ++j)
                    b[j] = *(const short8*)&Bs[swz(wc * 64 + j * 16 + (lane & 15), kb)];
                #pragma unroll
                for (int m = 0; m < 4; ++m)
                    #pragma unroll
                    for (int j = 0; j < 4; ++j)
                        acc[m][j] = __builtin_amdgcn_mfma_f32_16x16x32_bf16(a[m], b[j], acc[m][j], 0, 0, 0);
            }
        }
    }

    const int cl = lane & 15;
    const int rg = lane >> 4;
    const int h  = h0 + wc * 16 + cl;
    const float b_i = bh[0 * H_DIM + h];
    const float b_f = bh[1 * H_DIM + h];
    const float b_g = bh[2 * H_DIM + h];
    const float b_o = bh[3 * H_DIM + h];

    #pragma unroll
    for (int m = 0; m < 4; ++m) {
        #pragma unroll
        for (int r = 0; r < 4; ++r) {
            const int row = m0 + wr * 64 + m * 16 + rg * 4 + r;
            const float pi = acc[m][0][r] + b_i;
            const float pf = acc[m][1][r] + b_f;
            const float pg = acc[m][2][r] + b_g;
            const float po = acc[m][3][r] + b_o;
            const float iv = sigmoid_f(pi);
            const float fv = sigmoid_f(pf);
            const float gv = tanh_fast(pg);
            const float ov = sigmoid_f(po);
            const float cp = cprev[(size_t)row * H_DIM + h];
            const float cn = fv * cp + iv * gv;
            const float hn = ov * tanh_fast(cn);
            out[(size_t)row * H_DIM + h] = hn;
            out[(size_t)B_DIM * H_DIM + (size_t)row * H_DIM + h] = cn;
        }
    }
}

extern "C" void kernel_launch(void* const* d_in, const int* in_sizes, int n_in,
                              void* d_out, int out_size, void* d_ws, size_t ws_size,
                              hipStream_t stream) {
    const float* x     = (const float*)d_in[0];
    const float* hprev = (const float*)d_in[1];
    const float* cprev = (const float*)d_in[2];
    const float* Wx    = (const float*)d_in[3];
    const float* Wh    = (const float*)d_in[4];
    const float* bh    = (const float*)d_in[5];
    float* out = (float*)d_out;

    const size_t need = ((size_t)B_DIM * 2048 + (size_t)4096 * 2048) * sizeof(short);
    if (ws_size >= need && d_ws != nullptr) {
        (void)hipFuncSetAttribute((const void*)lstm_gemm_p8_kernel,
                                  hipFuncAttributeMaxDynamicSharedMemorySize, 131072);
        short* Aw = (short*)d_ws;                 // A_fw: 512 frags * 32768 shorts
        short* Bw = Aw + (size_t)512 * 32768;     // B_fw: 256 frags * 32768 shorts
        hipLaunchKernelGGL(convert_kernel, dim3(4096), dim3(256), 0, stream,
                           x, hprev, Wx, Wh, Aw, Bw);
        hipLaunchKernelGGL(lstm_gemm_p8_kernel, dim3(512), dim3(512), 131072, stream,
                           Aw, Bw, cprev, bh, out);
    } else {
        hipLaunchKernelGGL(lstm_fallback_kernel, dim3(2048), dim3(256), 0, stream,
                           x, hprev, cprev, Wx, Wh, bh, out);
    }
}